// Round 16
// baseline (57.712 us; speedup 1.0000x reference)
//
#include <hip/hip_runtime.h>
#include <cstddef>

// Problem constants
#define NPT 1024   // points
#define KNB 32     // neighbors
#define NR  33     // rows per point: 32 neighbors + x (row 32)

typedef __attribute__((ext_vector_type(8))) _Float16 half8v;  // 8 f16 (4 VGPRs)
typedef __attribute__((ext_vector_type(4))) float float4v;    // MFMA acc
typedef __attribute__((ext_vector_type(2))) float float2v;    // VOP3P pk ops

union fragU { unsigned u[4]; half8v v; };
union f4u { float4 f4; float2v f2[2]; };

// f32 -> f16 weight conversion (W1: 65536 el, W2: 32768 el)
__global__ __launch_bounds__(256) void wconv_kernel(
        const float* __restrict__ W1, const float* __restrict__ W2,
        _Float16* __restrict__ W1f, _Float16* __restrict__ W2f) {
    int idx = blockIdx.x * 256 + threadIdx.x;
    if (idx < 65536) W1f[idx] = (_Float16)W1[idx];
    else if (idx < 65536 + 32768) W2f[idx - 65536] = (_Float16)W2[idx - 65536];
}

// ---------------------------------------------------------------------------
// agg phase (in-LDS), 4 waves: wave wv owns cols [wv*64, wv*64+64) (NT=4).
// na = rownorm(sgnroot(X (x) S + S (x) X)) . rows^T -> Nh (f16).
// r13-proven frag-gen: packed f32 fma; f32 sqrt; cvt_pkrtz mag (sign-free)
// | cvt_pkrtz(a) sign bits; rloc packed f32; shfl_xor rnorm reduce.
// kt unrolled x2 for load/MFMA overlap (ILP).
// ---------------------------------------------------------------------------
template<int F>
__device__ __forceinline__ void agg_phase(
        const _Float16 (*Rh)[264], _Float16 (*Nh)[264],
        const float* Xs, const float* Ss, int wv, int lane) {
    const int nbase = wv * 64;
    const int kch = (nbase / F) * F;           // channel k-offset (block-diag A)
    const int l15 = lane & 15, lg = lane >> 4;

    float Xn[4], Sn[4];
    #pragma unroll
    for (int i = 0; i < 4; ++i) {
        int col = nbase + i * 16 + l15;
        Xn[i] = Xs[col]; Sn[i] = Ss[col];
    }

    float4v acc[3][4] = {};
    float rn[4] = {0.f, 0.f, 0.f, 0.f};

    const int KT = F / 32;
    #pragma unroll 2
    for (int kt = 0; kt < KT; ++kt) {
        const int k0 = kch + kt * 32 + lg * 8;
        half8v af[3];
        af[0] = *reinterpret_cast<const half8v*>(&Rh[l15][k0]);
        af[1] = *reinterpret_cast<const half8v*>(&Rh[16 + l15][k0]);
        af[2] = half8v{};
        if (l15 == 0)
            af[2] = *reinterpret_cast<const half8v*>(&Rh[32][k0]);
        f4u xa0, xa1, sa0, sa1;
        xa0.f4 = *reinterpret_cast<const float4*>(&Xs[k0]);
        xa1.f4 = *reinterpret_cast<const float4*>(&Xs[k0 + 4]);
        sa0.f4 = *reinterpret_cast<const float4*>(&Ss[k0]);
        sa1.f4 = *reinterpret_cast<const float4*>(&Ss[k0 + 4]);
        const float2v xk2[4] = {xa0.f2[0], xa0.f2[1], xa1.f2[0], xa1.f2[1]};
        const float2v sk2[4] = {sa0.f2[0], sa0.f2[1], sa1.f2[0], sa1.f2[1]};
        #pragma unroll
        for (int ni = 0; ni < 4; ++ni) {
            const float xn = Xn[ni], sn = Sn[ni];
            fragU bf;
            float2v rloc2 = {0.f, 0.f};
            #pragma unroll
            for (int jj = 0; jj < 4; ++jj) {
                const float2v a = xn * sk2[jj] + xk2[jj] * sn;   // pk_mul+pk_fma
                const float r0 = __builtin_amdgcn_sqrtf(__builtin_fabsf(a.x));
                const float r1 = __builtin_amdgcn_sqrtf(__builtin_fabsf(a.y));
                rloc2 += (float2v){r0, r1};                      // pk_add
                const unsigned mag = __builtin_bit_cast(unsigned,
                    __builtin_amdgcn_cvt_pkrtz(r0, r1));         // sign bits 0
                const unsigned sgn = __builtin_bit_cast(unsigned,
                    __builtin_amdgcn_cvt_pkrtz(a.x, a.y)) & 0x80008000u;
                bf.u[jj] = mag | sgn;
            }
            rn[ni] += rloc2.x + rloc2.y;
            #pragma unroll
            for (int m = 0; m < 3; ++m)
                acc[m][ni] = __builtin_amdgcn_mfma_f32_16x16x32_f16(
                                 af[m], bf.v, acc[m][ni], 0, 0, 0);
        }
    }

    #pragma unroll
    for (int ni = 0; ni < 4; ++ni) {
        rn[ni] += __shfl_xor(rn[ni], 16);
        rn[ni] += __shfl_xor(rn[ni], 32);
        rn[ni] = __builtin_amdgcn_rcpf(rn[ni] + 1e-7f);
    }

    // epilogue: D layout col = lane&15, row = (lane>>4)*4 + reg -> Nh (f16)
    #pragma unroll
    for (int m = 0; m < 3; ++m) {
        const int rbase = m * 16 + (lg << 2);
        #pragma unroll
        for (int ni = 0; ni < 4; ++ni) {
            const int col = nbase + ni * 16 + l15;
            #pragma unroll
            for (int i = 0; i < 4; ++i) {
                int r = rbase + i;
                if (r < NR)
                    Nh[r][col] = (_Float16)(acc[m][ni][i] * rn[ni]);
            }
        }
    }
}

// ---------------------------------------------------------------------------
// proj phase (in-LDS), 4 waves: wave wv owns NTW = DOUT/64 n-tiles.
// f16 MFMA from Nh vs global f16 weights; BN+softsign epilogue as a single
// FMA per element. kt unrolled x2 so next-kt W loads issue under MFMAs.
// ---------------------------------------------------------------------------
template<int DOUT, int FP>
__device__ __forceinline__ void proj_phase(
        const _Float16 (*Nh)[264], _Float16 (*Rh)[264],
        float* Xs, float* Ss,
        const _Float16* __restrict__ Wf,
        const float* __restrict__ bias,
        const float* __restrict__ g, const float* __restrict__ be,
        const float* __restrict__ m, const float* __restrict__ var,
        int wv, int lane) {
    const int l15 = lane & 15, lg = lane >> 4;
    constexpr int NTW = DOUT / 64;             // n-tiles per wave (4 waves)
    const int nbase = wv * (NTW * 16);

    float4v acc[3][NTW] = {};

    #pragma unroll 2
    for (int kt = 0; kt < 8; ++kt) {           // K = 256 always
        const int k0 = kt * 32 + lg * 8;
        half8v ah[3];
        ah[0] = *reinterpret_cast<const half8v*>(&Nh[l15][k0]);
        ah[1] = *reinterpret_cast<const half8v*>(&Nh[16 + l15][k0]);
        ah[2] = half8v{};
        if (l15 == 0)
            ah[2] = *reinterpret_cast<const half8v*>(&Nh[32][k0]);
        #pragma unroll
        for (int ni = 0; ni < NTW; ++ni) {
            const int d = nbase + ni * 16 + l15;
            const half8v bh = *reinterpret_cast<const half8v*>(Wf + (size_t)d * 256 + k0);
            #pragma unroll
            for (int mi = 0; mi < 3; ++mi)
                acc[mi][ni] = __builtin_amdgcn_mfma_f32_16x16x32_f16(
                                  ah[mi], bh, acc[mi][ni], 0, 0, 0);
        }
    }

    // epilogue: h = acc*sc + hb; softsign -> Rh (f16) + Xs/Ss (f32)
    #pragma unroll
    for (int ni = 0; ni < NTW; ++ni) {
        const int col = nbase + ni * 16 + l15;
        const int c = (nbase + ni * 16) / FP;  // lane-uniform
        const float sc = g[c] * __builtin_amdgcn_rsqf(var[c] + 1e-5f);
        const float hb = (bias[col] - m[c]) * sc + be[c];
        float colsum = 0.f, xval = 0.f;
        #pragma unroll
        for (int mi = 0; mi < 3; ++mi) {
            const int rbase = mi * 16 + (lg << 2);
            #pragma unroll
            for (int i = 0; i < 4; ++i) {
                const int r = rbase + i;
                if (r < NR) {
                    float h = acc[mi][ni][i] * sc + hb;
                    h = h * __builtin_amdgcn_rcpf(1.f + __builtin_fabsf(h));
                    Rh[r][col] = (_Float16)h;
                    if (r < 32) colsum += h; else xval = h;  // r==32 only on lg==0
                }
            }
        }
        colsum += __shfl_xor(colsum, 16);
        colsum += __shfl_xor(colsum, 32);
        if (lg == 0) { Ss[col] = colsum; Xs[col] = xval; }
    }
}

// ---------------------------------------------------------------------------
// Fully fused per-point pipeline: one block (256 thr, 4 waves) per point.
// Grid = 1024 = 4 blocks/CU exactly (grid-capped occupancy); column-split
// across more blocks impossible (proj needs full K=256 of na).
// Tail after aggx runs entirely in wave 0: proj3's h stays in registers and
// the classifier head reads it via __shfl -- two barriers removed.
// ---------------------------------------------------------------------------
__global__ __launch_bounds__(256, 4) void fused_kernel(
        const float* __restrict__ x, const float* __restrict__ nbr,
        const _Float16* __restrict__ W1f, const float* __restrict__ b1,
        const float* __restrict__ g1, const float* __restrict__ be1,
        const float* __restrict__ m1, const float* __restrict__ v1,
        const _Float16* __restrict__ W2f, const float* __restrict__ b2,
        const float* __restrict__ g2, const float* __restrict__ be2,
        const float* __restrict__ m2, const float* __restrict__ v2,
        const float* __restrict__ W3, const float* __restrict__ b3,
        const float* __restrict__ g3, const float* __restrict__ be3,
        const float* __restrict__ m3, const float* __restrict__ v3,
        const float* __restrict__ Wc, const float* __restrict__ bc,
        float* __restrict__ out) {
    const int n_pt = blockIdx.x, t = threadIdx.x;
    const int lane = t & 63, wv = t >> 6;

    __shared__ __align__(16) _Float16 Rh[NR][264];   // current rows (f16)
    __shared__ __align__(16) _Float16 Nh[NR][264];   // na (f16)
    __shared__ __align__(16) float Xs[256], Ss[256]; // x-row / col-sums (f32)
    __shared__ float xa3[128];

    // ---- stage layer-1 input: thread t owns column t ----
    {
        const float* nb = nbr + (size_t)n_pt * (KNB * 256);
        float s = 0.f;
        #pragma unroll 4
        for (int k = 0; k < KNB; ++k) {
            float v = nb[k * 256 + t];
            Rh[k][t] = (_Float16)v;
            s += v;
        }
        Ss[t] = s;
        float xv = x[(size_t)n_pt * 256 + t];
        Rh[32][t] = (_Float16)xv;
        Xs[t] = xv;
    }
    __syncthreads();

    // ---- layer 1: C=1, F=256 -> D=256 ----
    agg_phase<256>(Rh, Nh, Xs, Ss, wv, lane);
    __syncthreads();
    proj_phase<256, 64>(Nh, Rh, Xs, Ss, W1f, b1, g1, be1, m1, v1, wv, lane);
    __syncthreads();

    // ---- layer 2: C=4, F=64 -> D=128 ----
    agg_phase<64>(Rh, Nh, Xs, Ss, wv, lane);
    __syncthreads();
    proj_phase<128, 16>(Nh, Rh, Xs, Ss, W2f, b2, g2, be2, m2, v2, wv, lane);
    __syncthreads();

    // ---- layer 3: x-row aggregation only (F=16 within 128 cols) ----
    if (t < 128) {
        const int base = (t >> 4) << 4;
        const float xv = Xs[t], sv = Ss[t];
        float racc = 0.f, acc = 0.f;
        #pragma unroll
        for (int y = 0; y < 16; ++y) {
            const float xy = Xs[base + y];
            const float a = xv * Ss[base + y] + xy * sv;
            const float r = __builtin_amdgcn_sqrtf(__builtin_fabsf(a));
            racc += r;
            acc += __builtin_copysignf(r, a) * xy;
        }
        xa3[t] = acc * __builtin_amdgcn_rcpf(racc + 1e-7f);
    }
    __syncthreads();

    // ---- layer-3 projection + head: wave 0 only, barrier-free ----
    if (wv == 0) {
        const int tt = lane & 31;                  // lanes 32-63 duplicate
        const float* w3 = W3 + (size_t)tt * 128;
        float acc = b3[tt];
        #pragma unroll 4
        for (int i = 0; i < 128; ++i) acc += w3[i] * xa3[i];
        float h = (acc - m3[tt]) * __builtin_amdgcn_rsqf(v3[tt] + 1e-5f)
                      * g3[tt] + be3[tt];
        h = h * __builtin_amdgcn_rcpf(1.f + __builtin_fabsf(h));
        // head: lane t<10 computes out[n][t]; h gathered via shfl (in-register)
        const int row = (lane < 10) ? lane : 0;
        const float* wc = Wc + (size_t)row * 32;
        float hacc = bc[row];
        #pragma unroll
        for (int i = 0; i < 32; ++i)
            hacc += wc[i] * __shfl(h, i);          // all 64 lanes participate
        if (lane < 10)
            out[(size_t)n_pt * 10 + lane] = hacc;
    }
}

extern "C" void kernel_launch(void* const* d_in, const int* in_sizes, int n_in,
                              void* d_out, int out_size, void* d_ws, size_t ws_size,
                              hipStream_t stream) {
    (void)in_sizes; (void)n_in; (void)out_size; (void)ws_size;
    const float* x   = (const float*)d_in[0];   // [1024,1,256]
    const float* nbr = (const float*)d_in[1];   // [1024,32,1,256]
    const float* W1  = (const float*)d_in[2];   const float* b1 = (const float*)d_in[3];
    const float* g1  = (const float*)d_in[4];   const float* be1 = (const float*)d_in[5];
    const float* m1  = (const float*)d_in[6];   const float* v1 = (const float*)d_in[7];
    const float* W2  = (const float*)d_in[8];   const float* b2 = (const float*)d_in[9];
    const float* g2  = (const float*)d_in[10];  const float* be2 = (const float*)d_in[11];
    const float* m2  = (const float*)d_in[12];  const float* v2 = (const float*)d_in[13];
    const float* W3  = (const float*)d_in[14];  const float* b3 = (const float*)d_in[15];
    const float* g3  = (const float*)d_in[16];  const float* be3 = (const float*)d_in[17];
    const float* m3  = (const float*)d_in[18];  const float* v3 = (const float*)d_in[19];
    const float* Wc  = (const float*)d_in[20];  const float* bc = (const float*)d_in[21];
    float* out = (float*)d_out;

    // Workspace: f16 weights
    _Float16* W1f = (_Float16*)d_ws;
    _Float16* W2f = W1f + 65536;

    wconv_kernel<<<dim3((65536 + 32768 + 255) / 256), dim3(256), 0, stream>>>(
        W1, W2, W1f, W2f);
    fused_kernel<<<dim3(NPT), dim3(256), 0, stream>>>(
        x, nbr,
        W1f, b1, g1, be1, m1, v1,
        W2f, b2, g2, be2, m2, v2,
        W3, b3, g3, be3, m3, v3, Wc, bc, out);
}

// Round 17
// 51.085 us; speedup vs baseline: 1.1297x; 1.1297x over previous
//
#include <hip/hip_runtime.h>
#include <cstddef>

// Problem constants
#define NPT 1024   // points
#define KNB 32     // neighbors
#define NR  33     // rows per point: 32 neighbors + x (row 32)

typedef __attribute__((ext_vector_type(8))) _Float16 half8v;  // 8 f16 (4 VGPRs)
typedef __attribute__((ext_vector_type(4))) float float4v;    // MFMA acc
typedef __attribute__((ext_vector_type(2))) float float2v;    // VOP3P pk ops

union fragU { unsigned u[4]; half8v v; };
union f4u { float4 f4; float2v f2[2]; };

// f32 -> f16 weight conversion (W1: 65536 el, W2: 32768 el)
__global__ __launch_bounds__(256) void wconv_kernel(
        const float* __restrict__ W1, const float* __restrict__ W2,
        _Float16* __restrict__ W1f, _Float16* __restrict__ W2f) {
    int idx = blockIdx.x * 256 + threadIdx.x;
    if (idx < 65536) W1f[idx] = (_Float16)W1[idx];
    else if (idx < 65536 + 32768) W2f[idx - 65536] = (_Float16)W2[idx - 65536];
}

// ---------------------------------------------------------------------------
// agg phase (in-LDS), 4 waves: wave wv owns cols [wv*64, wv*64+64) (NT=4).
// na = rownorm(sgnroot(X (x) S + S (x) X)) . rows^T -> Nh (f16).
// sgnroot(a) ~ copysign(sqrt|a|, a) (max(.,1e-8) invisible at f16).
// A-pair computed with packed f32 (v_pk_mul/v_pk_fma); sqrt output is
// non-negative so cvt_pkrtz(r0,r1) needs no magnitude mask; sign bits from
// cvt_pkrtz(a0,a1). rloc accumulated as packed float2 (halved chain).
// ---------------------------------------------------------------------------
template<int F>
__device__ __forceinline__ void agg_phase(
        const _Float16 (*Rh)[264], _Float16 (*Nh)[264],
        const float* Xs, const float* Ss, int wv, int lane) {
    const int nbase = wv * 64;
    const int kch = (nbase / F) * F;           // channel k-offset (block-diag A)
    const int l15 = lane & 15, lg = lane >> 4;

    float Xn[4], Sn[4];
    #pragma unroll
    for (int i = 0; i < 4; ++i) {
        int col = nbase + i * 16 + l15;
        Xn[i] = Xs[col]; Sn[i] = Ss[col];
    }

    float4v acc[3][4] = {};
    float rn[4] = {0.f, 0.f, 0.f, 0.f};

    const int KT = F / 32;
    for (int kt = 0; kt < KT; ++kt) {
        const int k0 = kch + kt * 32 + lg * 8;
        half8v af[3];
        af[0] = *reinterpret_cast<const half8v*>(&Rh[l15][k0]);
        af[1] = *reinterpret_cast<const half8v*>(&Rh[16 + l15][k0]);
        af[2] = half8v{};
        if (l15 == 0)
            af[2] = *reinterpret_cast<const half8v*>(&Rh[32][k0]);
        f4u xa0, xa1, sa0, sa1;
        xa0.f4 = *reinterpret_cast<const float4*>(&Xs[k0]);
        xa1.f4 = *reinterpret_cast<const float4*>(&Xs[k0 + 4]);
        sa0.f4 = *reinterpret_cast<const float4*>(&Ss[k0]);
        sa1.f4 = *reinterpret_cast<const float4*>(&Ss[k0 + 4]);
        const float2v xk2[4] = {xa0.f2[0], xa0.f2[1], xa1.f2[0], xa1.f2[1]};
        const float2v sk2[4] = {sa0.f2[0], sa0.f2[1], sa1.f2[0], sa1.f2[1]};
        #pragma unroll
        for (int ni = 0; ni < 4; ++ni) {
            const float xn = Xn[ni], sn = Sn[ni];
            fragU bf;
            float2v rloc2 = {0.f, 0.f};
            #pragma unroll
            for (int jj = 0; jj < 4; ++jj) {
                const float2v a = xn * sk2[jj] + xk2[jj] * sn;   // pk_mul+pk_fma
                const float r0 = __builtin_amdgcn_sqrtf(__builtin_fabsf(a.x));
                const float r1 = __builtin_amdgcn_sqrtf(__builtin_fabsf(a.y));
                rloc2 += (float2v){r0, r1};                      // pk_add
                const unsigned mag = __builtin_bit_cast(unsigned,
                    __builtin_amdgcn_cvt_pkrtz(r0, r1));         // sign bits 0
                const unsigned sgn = __builtin_bit_cast(unsigned,
                    __builtin_amdgcn_cvt_pkrtz(a.x, a.y)) & 0x80008000u;
                bf.u[jj] = mag | sgn;
            }
            rn[ni] += rloc2.x + rloc2.y;
            #pragma unroll
            for (int m = 0; m < 3; ++m)
                acc[m][ni] = __builtin_amdgcn_mfma_f32_16x16x32_f16(
                                 af[m], bf.v, acc[m][ni], 0, 0, 0);
        }
    }

    #pragma unroll
    for (int ni = 0; ni < 4; ++ni) {
        rn[ni] += __shfl_xor(rn[ni], 16);
        rn[ni] += __shfl_xor(rn[ni], 32);
        rn[ni] = __builtin_amdgcn_rcpf(rn[ni] + 1e-7f);
    }

    // epilogue: D layout col = lane&15, row = (lane>>4)*4 + reg -> Nh (f16)
    #pragma unroll
    for (int m = 0; m < 3; ++m) {
        const int rbase = m * 16 + (lg << 2);
        #pragma unroll
        for (int ni = 0; ni < 4; ++ni) {
            const int col = nbase + ni * 16 + l15;
            #pragma unroll
            for (int i = 0; i < 4; ++i) {
                int r = rbase + i;
                if (r < NR)
                    Nh[r][col] = (_Float16)(acc[m][ni][i] * rn[ni]);
            }
        }
    }
}

// ---------------------------------------------------------------------------
// proj phase (in-LDS), 4 waves: wave wv owns NTW = DOUT/64 n-tiles.
// f16 MFMA from Nh vs global f16 weights; BN+softsign epilogue as a single
// FMA per element (hb = (bs-mm)*sc+bb precomputed per ni).
// ---------------------------------------------------------------------------
template<int DOUT, int FP>
__device__ __forceinline__ void proj_phase(
        const _Float16 (*Nh)[264], _Float16 (*Rh)[264],
        float* Xs, float* Ss,
        const _Float16* __restrict__ Wf,
        const float* __restrict__ bias,
        const float* __restrict__ g, const float* __restrict__ be,
        const float* __restrict__ m, const float* __restrict__ var,
        int wv, int lane) {
    const int l15 = lane & 15, lg = lane >> 4;
    constexpr int NTW = DOUT / 64;             // n-tiles per wave (4 waves)
    const int nbase = wv * (NTW * 16);

    float4v acc[3][NTW] = {};

    for (int kt = 0; kt < 8; ++kt) {           // K = 256 always
        const int k0 = kt * 32 + lg * 8;
        half8v ah[3];
        ah[0] = *reinterpret_cast<const half8v*>(&Nh[l15][k0]);
        ah[1] = *reinterpret_cast<const half8v*>(&Nh[16 + l15][k0]);
        ah[2] = half8v{};
        if (l15 == 0)
            ah[2] = *reinterpret_cast<const half8v*>(&Nh[32][k0]);
        #pragma unroll
        for (int ni = 0; ni < NTW; ++ni) {
            const int d = nbase + ni * 16 + l15;
            const half8v bh = *reinterpret_cast<const half8v*>(Wf + (size_t)d * 256 + k0);
            #pragma unroll
            for (int mi = 0; mi < 3; ++mi)
                acc[mi][ni] = __builtin_amdgcn_mfma_f32_16x16x32_f16(
                                  ah[mi], bh, acc[mi][ni], 0, 0, 0);
        }
    }

    // epilogue: h = acc*sc + hb; softsign -> Rh (f16) + Xs/Ss (f32)
    #pragma unroll
    for (int ni = 0; ni < NTW; ++ni) {
        const int col = nbase + ni * 16 + l15;
        const int c = (nbase + ni * 16) / FP;  // lane-uniform
        const float sc = g[c] * __builtin_amdgcn_rsqf(var[c] + 1e-5f);
        const float hb = (bias[col] - m[c]) * sc + be[c];
        float colsum = 0.f, xval = 0.f;
        #pragma unroll
        for (int mi = 0; mi < 3; ++mi) {
            const int rbase = mi * 16 + (lg << 2);
            #pragma unroll
            for (int i = 0; i < 4; ++i) {
                const int r = rbase + i;
                if (r < NR) {
                    float h = acc[mi][ni][i] * sc + hb;
                    h = h * __builtin_amdgcn_rcpf(1.f + __builtin_fabsf(h));
                    Rh[r][col] = (_Float16)h;
                    if (r < 32) colsum += h; else xval = h;  // r==32 only on lg==0
                }
            }
        }
        colsum += __shfl_xor(colsum, 16);
        colsum += __shfl_xor(colsum, 32);
        if (lg == 0) { Ss[col] = colsum; Xs[col] = xval; }
    }
}

// ---------------------------------------------------------------------------
// Fully fused per-point pipeline: one block (256 thr, 4 waves) per point.
// (256,4): VGPR cap 128 (fit from r6-r10: cap = 2048/(arg*waves_per_block)
// per SIMD). LDS 37.4 KB -> 4 blocks/CU; independent blocks drift into
// different phases (VALU-agg overlaps MFMA-proj across blocks) -- measured
// better than 512-thr variants (r8-r10), in-block pipelining (r14),
// trans/MFMA rebalance (r15), and kt-unroll/barrier cuts (r16).
// ---------------------------------------------------------------------------
__global__ __launch_bounds__(256, 4) void fused_kernel(
        const float* __restrict__ x, const float* __restrict__ nbr,
        const _Float16* __restrict__ W1f, const float* __restrict__ b1,
        const float* __restrict__ g1, const float* __restrict__ be1,
        const float* __restrict__ m1, const float* __restrict__ v1,
        const _Float16* __restrict__ W2f, const float* __restrict__ b2,
        const float* __restrict__ g2, const float* __restrict__ be2,
        const float* __restrict__ m2, const float* __restrict__ v2,
        const float* __restrict__ W3, const float* __restrict__ b3,
        const float* __restrict__ g3, const float* __restrict__ be3,
        const float* __restrict__ m3, const float* __restrict__ v3,
        const float* __restrict__ Wc, const float* __restrict__ bc,
        float* __restrict__ out) {
    const int n_pt = blockIdx.x, t = threadIdx.x;
    const int lane = t & 63, wv = t >> 6;

    __shared__ __align__(16) _Float16 Rh[NR][264];   // current rows (f16)
    __shared__ __align__(16) _Float16 Nh[NR][264];   // na (f16)
    __shared__ __align__(16) float Xs[256], Ss[256]; // x-row / col-sums (f32)
    __shared__ float xa3[128], hs3[32];

    // ---- stage layer-1 input: thread t owns column t ----
    {
        const float* nb = nbr + (size_t)n_pt * (KNB * 256);
        float s = 0.f;
        #pragma unroll 4
        for (int k = 0; k < KNB; ++k) {
            float v = nb[k * 256 + t];
            Rh[k][t] = (_Float16)v;
            s += v;
        }
        Ss[t] = s;
        float xv = x[(size_t)n_pt * 256 + t];
        Rh[32][t] = (_Float16)xv;
        Xs[t] = xv;
    }
    __syncthreads();

    // ---- layer 1: C=1, F=256 -> D=256 ----
    agg_phase<256>(Rh, Nh, Xs, Ss, wv, lane);
    __syncthreads();
    proj_phase<256, 64>(Nh, Rh, Xs, Ss, W1f, b1, g1, be1, m1, v1, wv, lane);
    __syncthreads();

    // ---- layer 2: C=4, F=64 -> D=128 ----
    agg_phase<64>(Rh, Nh, Xs, Ss, wv, lane);
    __syncthreads();
    proj_phase<128, 16>(Nh, Rh, Xs, Ss, W2f, b2, g2, be2, m2, v2, wv, lane);
    __syncthreads();

    // ---- layer 3: x-row aggregation only (F=16 within 128 cols) ----
    if (t < 128) {
        const int base = (t >> 4) << 4;
        const float xv = Xs[t], sv = Ss[t];
        float racc = 0.f, acc = 0.f;
        #pragma unroll
        for (int y = 0; y < 16; ++y) {
            const float xy = Xs[base + y];
            const float a = xv * Ss[base + y] + xy * sv;
            const float r = __builtin_amdgcn_sqrtf(__builtin_fabsf(a));
            racc += r;
            acc += __builtin_copysignf(r, a) * xy;
        }
        xa3[t] = acc * __builtin_amdgcn_rcpf(racc + 1e-7f);
    }
    __syncthreads();

    // ---- layer-3 projection + BN + softsign ----
    if (t < 32) {
        const float* w = W3 + (size_t)t * 128;
        float acc = b3[t];
        #pragma unroll 4
        for (int i = 0; i < 128; ++i) acc += w[i] * xa3[i];
        float h = (acc - m3[t]) * __builtin_amdgcn_rsqf(v3[t] + 1e-5f) * g3[t] + be3[t];
        hs3[t] = h * __builtin_amdgcn_rcpf(1.f + __builtin_fabsf(h));
    }
    __syncthreads();

    // ---- classifier head ----
    if (t < 10) {
        const float* w = Wc + (size_t)t * 32;
        float acc = bc[t];
        #pragma unroll
        for (int i = 0; i < 32; ++i) acc += w[i] * hs3[i];
        out[(size_t)n_pt * 10 + t] = acc;
    }
}

extern "C" void kernel_launch(void* const* d_in, const int* in_sizes, int n_in,
                              void* d_out, int out_size, void* d_ws, size_t ws_size,
                              hipStream_t stream) {
    (void)in_sizes; (void)n_in; (void)out_size; (void)ws_size;
    const float* x   = (const float*)d_in[0];   // [1024,1,256]
    const float* nbr = (const float*)d_in[1];   // [1024,32,1,256]
    const float* W1  = (const float*)d_in[2];   const float* b1 = (const float*)d_in[3];
    const float* g1  = (const float*)d_in[4];   const float* be1 = (const float*)d_in[5];
    const float* m1  = (const float*)d_in[6];   const float* v1 = (const float*)d_in[7];
    const float* W2  = (const float*)d_in[8];   const float* b2 = (const float*)d_in[9];
    const float* g2  = (const float*)d_in[10];  const float* be2 = (const float*)d_in[11];
    const float* m2  = (const float*)d_in[12];  const float* v2 = (const float*)d_in[13];
    const float* W3  = (const float*)d_in[14];  const float* b3 = (const float*)d_in[15];
    const float* g3  = (const float*)d_in[16];  const float* be3 = (const float*)d_in[17];
    const float* m3  = (const float*)d_in[18];  const float* v3 = (const float*)d_in[19];
    const float* Wc  = (const float*)d_in[20];  const float* bc = (const float*)d_in[21];
    float* out = (float*)d_out;

    // Workspace: f16 weights
    _Float16* W1f = (_Float16*)d_ws;
    _Float16* W2f = W1f + 65536;

    wconv_kernel<<<dim3((65536 + 32768 + 255) / 256), dim3(256), 0, stream>>>(
        W1, W2, W1f, W2f);
    fused_kernel<<<dim3(NPT), dim3(256), 0, stream>>>(
        x, nbr,
        W1f, b1, g1, be1, m1, v1,
        W2f, b2, g2, be2, m2, v2,
        W3, b3, g3, be3, m3, v3, Wc, bc, out);
}